// Round 7
// baseline (3867.063 us; speedup 1.0000x reference)
//
#include <hip/hip_runtime.h>
#include <hip/hip_cooperative_groups.h>

namespace cg = cooperative_groups;

// ConvLSTM1D: B=8, T=128, CIN=64, COUT=64, H=256
// R7 = R6 (persistent, x/h wave-specialized, flag sync, no L2-nuking fences)
//      + PIPELINED h-gather: wave-cooperative global_load_dwordx4 sc0 sc1
//        (16 in flight, one vmcnt drain) replacing 64 serial per-element
//        system-atomic loads (~45K cyc/step -> ~2K cyc/step), and
//      + vectorized x staging (dwordx4) with the same scatter pattern.
// Block = (b, coz of 2 co) x all 256 p; 512 threads; grid 256 (1 block/CU).
//   waves 0-3 (kh=0): x-half of K (ic 0..63); waves 4-7 (kh=1): h-half.

constexpr int Bn    = 8;
constexpr int Tn    = 128;
constexpr int CINn  = 64;
constexpr int COUTn = 64;
constexpr int Hn    = 256;
constexpr int NFLAG = Bn * Tn * 32;                              // 32768 words
constexpr size_t LDS_BYTES = (size_t)(258 * 128 + 8 * 256) * 4;  // 140288

__device__ __forceinline__ float sigmoidf_(float v) {
    return 1.0f / (1.0f + __expf(-v));
}
__device__ __forceinline__ void store_thru(float* p, float v) {
    __hip_atomic_store(p, v, __ATOMIC_RELAXED, __HIP_MEMORY_SCOPE_SYSTEM);
}
// Coherence-safe (L1/L2-bypass) but PIPELINED 16B load; caller must
// s_waitcnt vmcnt(0) before consuming results.
__device__ __forceinline__ float4 load_f4_sys(const float* p) {
    float4 v;
    asm volatile("global_load_dwordx4 %0, %1, off sc0 sc1"
                 : "=v"(v) : "v"(p) : "memory");
    return v;
}

template <bool USE_FLAGS>
__global__ __launch_bounds__(512, 2) void convlstm_persist(
    const float* __restrict__ x,     // [B][T][CIN][H]
    const float* __restrict__ h0,    // [B][COUT][H]
    const float* __restrict__ c0,    // [B][COUT][H]
    const float* __restrict__ wg,    // [4*COUT][128][3]
    const float* __restrict__ bias,  // [4*COUT]
    const float* __restrict__ wci,   // [COUT][H]
    const float* __restrict__ wcf,   // [COUT][H]
    const float* __restrict__ wco,   // [COUT][H]
    float* __restrict__ hs,          // [B][T][COUT][H]
    float* __restrict__ cs,          // [B][T][COUT][H]
    unsigned int* flags)             // [B][T][32]
{
    extern __shared__ float lds[];
    float*  cat  = lds;                         // [258][128] swizzled
    float*  part = lds + 258 * 128;             // [8][256]
    float4* cat4 = (float4*)cat;

    const int tid = threadIdx.x;
    const int blk = blockIdx.x;
    const int b   = blk & 7;
    const int coz = blk >> 3;                   // 0..31
    const int co0 = coz * 2;
    const int kh  = tid >> 8;                   // 0 = x-waves, 1 = h-waves
    const int p_l = tid & 255;

    // cooperative-staging coordinates (within each 4-wave half)
    const int wl   = (tid >> 6) & 3;            // wave-in-half 0..3
    const int lane = tid & 63;
    const int chl  = lane >> 2;                 // 0..15 channel-in-wave
    const int pq   = lane & 3;                  // p-quad-in-16

    // halo rows 0 / 257 (p=-1, p=256): zero, t-invariant
    if (tid < 32)       cat4[tid] = make_float4(0.f, 0.f, 0.f, 0.f);
    else if (tid < 64)  cat4[257 * 32 + (tid - 32)] = make_float4(0.f, 0.f, 0.f, 0.f);

    float bias_r[8];
#pragma unroll
    for (int k = 0; k < 8; ++k)
        bias_r[k] = bias[(k >> 1) * COUTn + co0 + (k & 1)];

    float c_reg[2] = {0.f, 0.f}, wci_r[2], wcf_r[2], wco_r[2];
    if (kh == 1) {
#pragma unroll
        for (int j = 0; j < 2; ++j) {
            const int cidx = (co0 + j) * Hn + p_l;
            wci_r[j] = wci[cidx];
            wcf_r[j] = wcf[cidx];
            wco_r[j] = wco[cidx];
            c_reg[j] = c0[b * COUTn * Hn + cidx];
        }
    }

    const float4* __restrict__ w4 = (const float4*)wg;   // block-uniform

    cg::grid_group grid = cg::this_grid();

    // ---- staging: wave covers 16 channels x 256 p, dwordx4 over p ----
    auto stage_x = [&](const float* xs) {       // quads 0..15 (cached loads)
        float4 xv[16];
#pragma unroll
        for (int r = 0; r < 16; ++r)
            xv[r] = *(const float4*)(xs + (size_t)(wl * 16 + chl) * Hn
                                        + r * 16 + pq * 4);
        const int ic = wl * 16 + chl;
        const int cq = ic >> 2, cl = ic & 3;
#pragma unroll
        for (int r = 0; r < 16; ++r) {
            const float v[4] = {xv[r].x, xv[r].y, xv[r].z, xv[r].w};
#pragma unroll
            for (int k = 0; k < 4; ++k) {
                const int row = r * 16 + pq * 4 + k + 1;
                cat[row * 128 + ((cq ^ (row & 31)) << 2) + cl] = v[k];
            }
        }
    };
    auto stage_h = [&](const float* hsrc) {     // quads 16..31 (sc0sc1 loads)
        float4 hv[16];
#pragma unroll
        for (int r = 0; r < 16; ++r)
            hv[r] = load_f4_sys(hsrc + (size_t)(wl * 16 + chl) * Hn
                                     + r * 16 + pq * 4);
        asm volatile("s_waitcnt vmcnt(0)" ::: "memory");
        __builtin_amdgcn_sched_barrier(0);
        const int ch = 64 + wl * 16 + chl;
        const int cq = ch >> 2, cl = ch & 3;
#pragma unroll
        for (int r = 0; r < 16; ++r) {
            const float v[4] = {hv[r].x, hv[r].y, hv[r].z, hv[r].w};
#pragma unroll
            for (int k = 0; k < 4; ++k) {
                const int row = r * 16 + pq * 4 + k + 1;
                cat[row * 128 + ((cq ^ (row & 31)) << 2) + cl] = v[k];
            }
        }
    };
    auto gemm_half = [&](int q0, float* acc) {  // 16 quads starting q0
        const int r0 = p_l, r1 = p_l + 1, r2 = p_l + 2;
        const int s0 = r0 & 31, s1 = r1 & 31, s2 = r2 & 31;
#pragma unroll 2
        for (int icq = q0; icq < q0 + 16; ++icq) {
            const float4 a0 = cat4[r0 * 32 + (icq ^ s0)];
            const float4 a1 = cat4[r1 * 32 + (icq ^ s1)];
            const float4 a2 = cat4[r2 * 32 + (icq ^ s2)];
            const float in0[4] = {a0.x, a0.y, a0.z, a0.w};
            const float in1[4] = {a1.x, a1.y, a1.z, a1.w};
            const float in2[4] = {a2.x, a2.y, a2.z, a2.w};
#pragma unroll
            for (int k = 0; k < 8; ++k) {
                const int wrow = (k >> 1) * COUTn + co0 + (k & 1);
                const float4 w0 = w4[(size_t)wrow * 96 + icq * 3 + 0];
                const float4 w1 = w4[(size_t)wrow * 96 + icq * 3 + 1];
                const float4 w2 = w4[(size_t)wrow * 96 + icq * 3 + 2];
                const float wr_[12] = {w0.x, w0.y, w0.z, w0.w,
                                       w1.x, w1.y, w1.z, w1.w,
                                       w2.x, w2.y, w2.z, w2.w};
#pragma unroll
                for (int i = 0; i < 4; ++i) {
                    acc[k] = fmaf(wr_[3 * i + 0], in0[i],
                              fmaf(wr_[3 * i + 1], in1[i],
                              fmaf(wr_[3 * i + 2], in2[i], acc[k])));
                }
            }
        }
    };

    // ---- prologue: stage x_0 ----
    if (kh == 0) stage_x(x + (size_t)(b * Tn + 0) * CINn * Hn);
    __syncthreads();

    for (int t = 0; t < Tn; ++t) {
        float acc[8];

        // ======== P0: x-GEMM  ||  spin + pipelined h-gather ========
        if (kh == 0) {
#pragma unroll
            for (int k = 0; k < 8; ++k) acc[k] = bias_r[k];
            gemm_half(0, acc);
        } else {
            if (USE_FLAGS && t > 0) {
                const unsigned int* fp =
                    flags + (size_t)(b * Tn + (t - 1)) * 32 + (tid & 31);
                while (true) {
                    unsigned int v = __hip_atomic_load(fp, __ATOMIC_RELAXED,
                                                       __HIP_MEMORY_SCOPE_SYSTEM);
                    if (__all(v >= 4u)) break;
                    __builtin_amdgcn_s_sleep(2);
                }
            }
            const float* hp = (t == 0)
                ? (h0 + (size_t)b * COUTn * Hn)
                : (hs + (size_t)(b * Tn + (t - 1)) * COUTn * Hn);
            stage_h(hp);
        }
        __syncthreads();   // #1

        // ======== P1: partials + x(t+1) prefetch-stage  ||  h-GEMM ========
        if (kh == 0) {
#pragma unroll
            for (int k = 0; k < 8; ++k) part[k * Hn + p_l] = acc[k];
            if (t + 1 < Tn)
                stage_x(x + (size_t)(b * Tn + (t + 1)) * CINn * Hn);
        } else {
#pragma unroll
            for (int k = 0; k < 8; ++k) acc[k] = 0.f;
            gemm_half(16, acc);
        }
        __syncthreads();   // #2

        // ======== P2: gates + stores + flag release (h-waves) ========
        if (kh == 1) {
#pragma unroll
            for (int j = 0; j < 2; ++j) {
                const float pi  = part[(0 + j) * Hn + p_l] + acc[0 + j];
                const float pf  = part[(2 + j) * Hn + p_l] + acc[2 + j];
                const float pgv = part[(4 + j) * Hn + p_l] + acc[4 + j];
                const float po  = part[(6 + j) * Hn + p_l] + acc[6 + j];

                const float cprev = c_reg[j];
                const float iv = sigmoidf_(pi + wci_r[j] * cprev);
                const float fv = sigmoidf_(pf + wcf_r[j] * cprev);
                const float gv = tanhf(pgv);
                const float cn = fv * cprev + iv * gv;
                const float ov = sigmoidf_(po + wco_r[j] * cn);
                const float hn = ov * tanhf(cn);
                c_reg[j] = cn;

                const size_t oidx =
                    ((size_t)(b * Tn + t) * COUTn + co0 + j) * Hn + p_l;
                store_thru(hs + oidx, hn);
                store_thru(cs + oidx, cn);
            }
            if (USE_FLAGS) {
                if ((tid & 63) == 0) {
                    // release: drains this wave's stores to the coherence
                    // point before the count becomes visible
                    __hip_atomic_fetch_add(
                        flags + (size_t)(b * Tn + t) * 32 + coz, 1u,
                        __ATOMIC_RELEASE, __HIP_MEMORY_SCOPE_SYSTEM);
                }
            }
        }
        if (!USE_FLAGS) {
            __threadfence();
            grid.sync();
        }
    }
}

__global__ __launch_bounds__(256) void zero_flags(unsigned int* f, int n) {
    const int i = blockIdx.x * 256 + threadIdx.x;
    if (i < n)
        __hip_atomic_store(&f[i], 0u, __ATOMIC_RELAXED, __HIP_MEMORY_SCOPE_SYSTEM);
}

extern "C" void kernel_launch(void* const* d_in, const int* in_sizes, int n_in,
                              void* d_out, int out_size, void* d_ws, size_t ws_size,
                              hipStream_t stream) {
    (void)in_sizes; (void)n_in; (void)out_size;

    const float* x    = (const float*)d_in[0];
    const float* h0   = (const float*)d_in[1];
    const float* c0   = (const float*)d_in[2];
    const float* w    = (const float*)d_in[3];
    const float* bias = (const float*)d_in[4];
    const float* wci  = (const float*)d_in[5];
    const float* wcf  = (const float*)d_in[6];
    const float* wco  = (const float*)d_in[7];

    float* hs = (float*)d_out;
    float* cs = hs + (size_t)Bn * Tn * COUTn * Hn;
    unsigned int* flags = (unsigned int*)d_ws;

    const size_t flag_bytes = (size_t)NFLAG * sizeof(unsigned int);  // 128 KB
    const bool use_flags = (d_ws != nullptr) && (ws_size >= flag_bytes);

    void* args[] = {(void*)&x, (void*)&h0, (void*)&c0, (void*)&w,
                    (void*)&bias, (void*)&wci, (void*)&wcf, (void*)&wco,
                    (void*)&hs, (void*)&cs, (void*)&flags};

    if (use_flags) {
        hipFuncSetAttribute((const void*)convlstm_persist<true>,
                            hipFuncAttributeMaxDynamicSharedMemorySize,
                            (int)LDS_BYTES);
        zero_flags<<<(NFLAG + 255) / 256, 256, 0, stream>>>(flags, NFLAG);
        hipLaunchCooperativeKernel((const void*)convlstm_persist<true>,
                                   dim3(256), dim3(512), args,
                                   (unsigned int)LDS_BYTES, stream);
    } else {
        hipFuncSetAttribute((const void*)convlstm_persist<false>,
                            hipFuncAttributeMaxDynamicSharedMemorySize,
                            (int)LDS_BYTES);
        hipLaunchCooperativeKernel((const void*)convlstm_persist<false>,
                                   dim3(256), dim3(512), args,
                                   (unsigned int)LDS_BYTES, stream);
    }
}